// Round 11
// baseline (44.364 us; speedup 1.0000x reference)
//
#include <hip/hip_runtime.h>
#include <math.h>

#define NCTX 2048
#define NT 34

typedef float f4 __attribute__((ext_vector_type(4)));
typedef float f2 __attribute__((ext_vector_type(2)));

// workspace float offsets
#define OFF_XR 0u         // 4*256
#define OFF_XI 1024u      // 4*256
#define OFF_TR 2048u      // 4*34*16*16*2 = 69632
#define OFF_BE 71680u     // 4*16*16 = 1024
#define OFF_GI 72704u     // 4*16*768*2 = 98304
#define OFF_GJ 171008u    // 4*16*768*2 = 98304

__device__ __forceinline__ float siglog(float v) {
  return copysignf(log1pf(fabsf(v)), v);
}

__device__ __forceinline__ f4 ntload4(const float* p) {
  return __builtin_nontemporal_load((const f4*)p);
}

// N1: row-quartet GEMV (p, p+256, p+512, p+768) + siglog mix -> xr/xi.
// 256 blocks = exactly 1/CU (single dispatch round, no tail).
__global__ __launch_bounds__(256) void n1_xm(const float* __restrict__ x,
                                             const float* __restrict__ Wc,
                                             const float* __restrict__ bc,
                                             float* __restrict__ xr,
                                             float* __restrict__ xi) {
  const int p = blockIdx.x;  // 0..255
  const int tid = threadIdx.x;
  const float* w0p = Wc + (size_t)p * NCTX;
  const float* w1p = Wc + (size_t)(p + 256) * NCTX;
  const float* w2p = Wc + (size_t)(p + 512) * NCTX;
  const float* w3p = Wc + (size_t)(p + 768) * NCTX;
  const f4* x4 = (const f4*)x;
  float a[4][4];  // [row][b]
  #pragma unroll
  for (int r = 0; r < 4; ++r)
    #pragma unroll
    for (int b = 0; b < 4; ++b) a[r][b] = 0.f;
  #pragma unroll
  for (int it = 0; it < 2; ++it) {
    int i = tid + it * 256;
    f4 wr0 = ntload4(w0p + i * 4);
    f4 wr1 = ntload4(w1p + i * 4);
    f4 wr2 = ntload4(w2p + i * 4);
    f4 wr3 = ntload4(w3p + i * 4);
    f4 v0 = x4[i];
    f4 v1 = x4[512 + i];
    f4 v2 = x4[1024 + i];
    f4 v3 = x4[1536 + i];
    a[0][0] += wr0.x * v0.x + wr0.y * v0.y + wr0.z * v0.z + wr0.w * v0.w;
    a[0][1] += wr0.x * v1.x + wr0.y * v1.y + wr0.z * v1.z + wr0.w * v1.w;
    a[0][2] += wr0.x * v2.x + wr0.y * v2.y + wr0.z * v2.z + wr0.w * v2.w;
    a[0][3] += wr0.x * v3.x + wr0.y * v3.y + wr0.z * v3.z + wr0.w * v3.w;
    a[1][0] += wr1.x * v0.x + wr1.y * v0.y + wr1.z * v0.z + wr1.w * v0.w;
    a[1][1] += wr1.x * v1.x + wr1.y * v1.y + wr1.z * v1.z + wr1.w * v1.w;
    a[1][2] += wr1.x * v2.x + wr1.y * v2.y + wr1.z * v2.z + wr1.w * v2.w;
    a[1][3] += wr1.x * v3.x + wr1.y * v3.y + wr1.z * v3.z + wr1.w * v3.w;
    a[2][0] += wr2.x * v0.x + wr2.y * v0.y + wr2.z * v0.z + wr2.w * v0.w;
    a[2][1] += wr2.x * v1.x + wr2.y * v1.y + wr2.z * v1.z + wr2.w * v1.w;
    a[2][2] += wr2.x * v2.x + wr2.y * v2.y + wr2.z * v2.z + wr2.w * v2.w;
    a[2][3] += wr2.x * v3.x + wr2.y * v3.y + wr2.z * v3.z + wr2.w * v3.w;
    a[3][0] += wr3.x * v0.x + wr3.y * v0.y + wr3.z * v0.z + wr3.w * v0.w;
    a[3][1] += wr3.x * v1.x + wr3.y * v1.y + wr3.z * v1.z + wr3.w * v1.w;
    a[3][2] += wr3.x * v2.x + wr3.y * v2.y + wr3.z * v2.z + wr3.w * v2.w;
    a[3][3] += wr3.x * v3.x + wr3.y * v3.y + wr3.z * v3.z + wr3.w * v3.w;
  }
  __shared__ float red[16][256];
  __shared__ float sums[16];
  #pragma unroll
  for (int r = 0; r < 4; ++r)
    #pragma unroll
    for (int b = 0; b < 4; ++b) red[r * 4 + b][tid] = a[r][b];
  __syncthreads();
  const int wv = tid >> 6, lane = tid & 63;
  #pragma unroll
  for (int q = 0; q < 4; ++q) {
    int combo = wv * 4 + q;  // combo = row*4 + b
    float s = red[combo][lane] + red[combo][lane + 64] +
              red[combo][lane + 128] + red[combo][lane + 192];
    #pragma unroll
    for (int off = 32; off > 0; off >>= 1) s += __shfl_down(s, off, 64);
    if (lane == 0) sums[combo] = s;
  }
  __syncthreads();
  if (tid < 8) {
    const int b = tid & 3, jsel = tid >> 2;
    const int j = p + jsel * 256;
    float d1 = sums[jsel * 4 + b] + bc[j];
    float d2 = sums[(2 + jsel) * 4 + b] + bc[j + 512];
    float v = d1 * siglog(d2);
    float* dst = (j & 1) ? xi : xr;
    dst[b * 256 + (j >> 1)] = v;
  }
}

// N2: blocks 0..543 = trans einsum tiles (t,c); blocks 544..607 = beta (b,n).
__global__ __launch_bounds__(256) void n2_trans_beta(
    const float* __restrict__ GR, const float* __restrict__ GIm,
    const float* __restrict__ xr, const float* __restrict__ xi,
    const float* __restrict__ wm, float* __restrict__ tr,
    float* __restrict__ beta) {
  const int u = blockIdx.x;
  const int tid = threadIdx.x;
  __shared__ __align__(16) float smem[10880];
  if (u < NT * 16) {
    const int t = u >> 4;
    const int c = u & 15;
    float* grT = smem;            // [16][260]
    float* giT = smem + 4160;     // [16][260]
    float* xr_s = smem + 8320;    // [1024]
    float* xi_s = smem + 9344;    // [1024]
    f2* red2 = (f2*)(smem + 10368);  // [4][64]
    const float* grp = GR + (size_t)(t * 16 + c) * 4096;
    const float* gip = GIm + (size_t)(t * 16 + c) * 4096;
    #pragma unroll
    for (int it = 0; it < 4; ++it) {
      int k = tid + it * 256;          // float4 index over [l][r]
      int l = k >> 2, q = (k & 3) * 4; // r-start
      f4 g = ntload4(grp + k * 4);
      grT[(q + 0) * 260 + l] = g.x; grT[(q + 1) * 260 + l] = g.y;
      grT[(q + 2) * 260 + l] = g.z; grT[(q + 3) * 260 + l] = g.w;
      f4 h = ntload4(gip + k * 4);
      giT[(q + 0) * 260 + l] = h.x; giT[(q + 1) * 260 + l] = h.y;
      giT[(q + 2) * 260 + l] = h.z; giT[(q + 3) * 260 + l] = h.w;
    }
    ((f4*)xr_s)[tid] = ((const f4*)xr)[tid];
    ((f4*)xi_s)[tid] = ((const f4*)xi)[tid];
    __syncthreads();
    const int r = tid & 15, b = (tid >> 4) & 3, lseg = tid >> 6;
    const f4* grv = (const f4*)&grT[r * 260 + lseg * 64];
    const f4* giv = (const f4*)&giT[r * 260 + lseg * 64];
    const f4* xrv = (const f4*)&xr_s[b * 256 + lseg * 64];
    const f4* xiv = (const f4*)&xi_s[b * 256 + lseg * 64];
    float are = 0.f, aim = 0.f;
    #pragma unroll
    for (int li = 0; li < 16; ++li) {
      f4 g = grv[li], gg = giv[li], vr = xrv[li], vi = xiv[li];
      are += vr.x * g.x - vi.x * gg.x;  aim += vr.x * gg.x + vi.x * g.x;
      are += vr.y * g.y - vi.y * gg.y;  aim += vr.y * gg.y + vi.y * g.y;
      are += vr.z * g.z - vi.z * gg.z;  aim += vr.z * gg.z + vi.z * g.z;
      are += vr.w * g.w - vi.w * gg.w;  aim += vr.w * gg.w + vi.w * g.w;
    }
    f2 rv; rv.x = are; rv.y = aim;
    red2[lseg * 64 + b * 16 + r] = rv;
    __syncthreads();
    if (tid < 64) {
      const int rr = tid & 15, bb = tid >> 4;
      f2 s0 = red2[0 * 64 + tid], s1 = red2[1 * 64 + tid];
      f2 s2 = red2[2 * 64 + tid], s3 = red2[3 * 64 + tid];
      float sre = s0.x + s1.x + s2.x + s3.x;
      float sim = s0.y + s1.y + s2.y + s3.y;
      float mag = sqrtf(sre * sre + sim * sim + 1e-12f);
      float scale = 256.f * mag / (256.f * mag + 1e-12f);
      size_t o = ((((size_t)bb * NT + t) * 16 + c) * 16 + rr) * 2;
      tr[o]     = sre * scale;
      tr[o + 1] = sim * scale;
    }
  } else {
    // beta block: (b, n)
    const int u2 = u - NT * 16;
    const int n = u2 & 15, b = u2 >> 4;
    float* xr_s = smem;            // 256
    float* xi_s = smem + 256;      // 256
    f2* redb = (f2*)(smem + 512);  // [16][16]
    xr_s[tid] = xr[b * 256 + tid];
    xi_s[tid] = xi[b * 256 + tid];
    __syncthreads();
    const int r = tid & 15, lseg = tid >> 4;
    const f2* wm2 = (const f2*)wm;
    float tre = 0.f, tim = 0.f;
    #pragma unroll
    for (int li = 0; li < 16; ++li) {
      int l = lseg * 16 + li;
      f2 w = wm2[(size_t)l * 256 + n * 16 + r];
      float vr = xr_s[l], vi = xi_s[l];
      tre += vr * w.x - vi * w.y;
      tim += vr * w.y + vi * w.x;
    }
    f2 rv; rv.x = tre; rv.y = tim;
    redb[lseg * 16 + r] = rv;
    __syncthreads();
    if (tid < 16) {
      float sr = 0.f, si = 0.f;
      #pragma unroll
      for (int s = 0; s < 16; ++s) { sr += redb[s * 16 + tid].x; si += redb[s * 16 + tid].y; }
      float val = sqrtf(sr * sr + si * si + 1e-12f);
      float m = val;
      #pragma unroll
      for (int off = 8; off > 0; off >>= 1) m = fmaxf(m, __shfl_xor(m, off, 16));
      float e = expf(val - m);
      float ss = e;
      #pragma unroll
      for (int off = 8; off > 0; off >>= 1) ss += __shfl_xor(ss, off, 16);
      beta[(b * 16 + n) * 16 + tid] = e / ss;
    }
  }
}

// N3 (k5): build si/sj, apply inv, beta-weighted r-sum.
// grid (c=16, b=4, z=6): which = z/3, h-segment = z%3; one h per thread.
__global__ __launch_bounds__(256) void k5_g(const float* __restrict__ space_i,
                                            const float* __restrict__ space_j,
                                            const float* __restrict__ invs,
                                            const float* __restrict__ tr,
                                            const float* __restrict__ beta,
                                            float* __restrict__ gI,
                                            float* __restrict__ gJ) {
  const int c = blockIdx.x, b = blockIdx.y;
  const int which = blockIdx.z / 3, seg = blockIdx.z % 3;
  const int tid = threadIdx.x;
  __shared__ float sh_beta[16];
  __shared__ float sh_shift[16][2];
  __shared__ float sh_z[16][16][2];  // [rt][r][comp]
  if (tid < 16) sh_beta[tid] = beta[(b * 16 + c) * 16 + tid];
  if (tid >= 32 && tid < 64) {
    int t2 = tid - 32;
    int r = t2 >> 1, comp = t2 & 1;
    sh_shift[r][comp] = tr[((((size_t)b * NT + which) * 16 + c) * 16 + r) * 2 + comp];
  }
  for (int idx = tid; idx < 512; idx += 256) {
    int rt = idx >> 5, r = (idx >> 1) & 15, comp = idx & 1;
    int t = 2 + which * 16 + rt;
    sh_z[rt][r][comp] = tr[((((size_t)b * NT + t) * 16 + c) * 16 + r) * 2 + comp];
  }
  const float inv_re = invs[c * 2], inv_im = invs[c * 2 + 1];
  __syncthreads();
  const f2* sp2 = (const f2*)(which == 0 ? space_i : space_j);
  sp2 += (size_t)c * 16 * 768;
  f2* gout = (f2*)(which == 0 ? gI : gJ);
  gout += (size_t)(b * 16 + c) * 768;
  const int h = seg * 256 + tid;
  float pos = ((float)h + 0.5f) * (16.f / 768.f) - 0.5f;
  pos = fminf(fmaxf(pos, 0.f), 15.f);
  int lo = (int)floorf(pos);
  int hi = min(lo + 1, 15);
  float w = pos - (float)lo;
  float accR = 0.f, accI = 0.f;
  #pragma unroll
  for (int r = 0; r < 16; ++r) {
    f2 sp = sp2[r * 768 + h];
    float spr = sp.x + sh_shift[r][0];
    float spi = sp.y + sh_shift[r][1];
    float ztr = sh_z[lo][r][0] * (1.f - w) + sh_z[hi][r][0] * w;
    float zti = sh_z[lo][r][1] * (1.f - w) + sh_z[hi][r][1] * w;
    float sre = spr * ztr - spi * zti;
    float sim = spr * zti + spi * ztr;
    float br = sh_beta[r];
    if (which == 0) {
      accR += br * sre;
      accI += br * sim;
    } else {
      float den = fmaxf(sre * sre + sim * sim, 1e-4f);
      float id = 1.f / den;
      accR += br * (inv_re * sre + inv_im * sim) * id;
      accI += br * (inv_im * sre - inv_re * sim) * id;
    }
  }
  f2 o;
  if (which == 0) {  // gI = cmul(sum, inv)  (cmul linear in first arg)
    o.x = accR * inv_re - accI * inv_im;
    o.y = accR * inv_im + accI * inv_re;
  } else {
    o.x = accR; o.y = accI;
  }
  gout[h] = o;
}

// N4 (k6): out[b][h][w] = sum_c (wRe*pc + wIm*ps). 32x32 tile, 2x2/thread,
// depth-4 prefetch with NAMED registers (indexed arrays go to scratch).
__global__ __launch_bounds__(256) void k6_out(const float* __restrict__ proj,
                                              const float* __restrict__ gI,
                                              const float* __restrict__ gJ,
                                              float* __restrict__ out) {
  const int w0 = blockIdx.x * 32;
  const int h0 = blockIdx.y * 32;
  const int tid = threadIdx.x;
  const int tw = tid & 15, th = tid >> 4;
  __shared__ f2 gIs[64][32];  // [b*16+c][hh]
  __shared__ f2 gJs[64][32];  // [b*16+c][ww]
  const f2* gI2 = (const f2*)gI;
  const f2* gJ2 = (const f2*)gJ;
  #pragma unroll
  for (int it = 0; it < 8; ++it) {
    int idx = tid + it * 256;
    int i = idx & 31, bcp = idx >> 5;
    gIs[bcp][i] = gI2[(size_t)bcp * 768 + h0 + i];
    gJs[bcp][i] = gJ2[(size_t)bcp * 768 + w0 + i];
  }
  __syncthreads();
  const float* pp = proj + ((size_t)(h0 + th * 2) * 384 + (w0 >> 1) + tw) * 4;
  float acc[4][4];
  #pragma unroll
  for (int b = 0; b < 4; ++b)
    #pragma unroll
    for (int q = 0; q < 4; ++q) acc[b][q] = 0.f;

  const size_t CS = (size_t)768 * 384 * 4;
  f4 pa0 = ntload4(pp);
  f4 pb0 = ntload4(pp + 384 * 4);
  f4 pa1 = ntload4(pp + CS);
  f4 pb1 = ntload4(pp + CS + 384 * 4);
  f4 pa2 = ntload4(pp + 2 * CS);
  f4 pb2 = ntload4(pp + 2 * CS + 384 * 4);
  f4 pa3 = ntload4(pp + 3 * CS);
  f4 pb3 = ntload4(pp + 3 * CS + 384 * 4);

#define K6_STEP(PA, PB, CCUR, CNEXT)                                         \
    {                                                                        \
      f4 c0 = PA, c1 = PB;                                                   \
      if ((CNEXT) < 16) {                                                    \
        size_t nxt = (size_t)(CNEXT) * CS;                                   \
        PA = ntload4(pp + nxt);                                              \
        PB = ntload4(pp + nxt + 384 * 4);                                    \
      }                                                                      \
      float rq00 = rsqrtf(c0.x * c0.x + c0.y * c0.y + 1e-12f);               \
      float rq01 = rsqrtf(c0.z * c0.z + c0.w * c0.w + 1e-12f);               \
      float rq10 = rsqrtf(c1.x * c1.x + c1.y * c1.y + 1e-12f);               \
      float rq11 = rsqrtf(c1.z * c1.z + c1.w * c1.w + 1e-12f);               \
      float pr00 = c0.x * rq00, pi00 = c0.y * rq00;                          \
      float pr01 = c0.z * rq01, pi01 = c0.w * rq01;                          \
      float pr10 = c1.x * rq10, pi10 = c1.y * rq10;                          \
      float pr11 = c1.z * rq11, pi11 = c1.w * rq11;                          \
      _Pragma("unroll")                                                      \
      for (int b = 0; b < 4; ++b) {                                          \
        f2 gi0 = gIs[b * 16 + (CCUR)][th * 2];                               \
        f2 gi1 = gIs[b * 16 + (CCUR)][th * 2 + 1];                           \
        f2 gj0 = gJs[b * 16 + (CCUR)][tw * 2];                               \
        f2 gj1 = gJs[b * 16 + (CCUR)][tw * 2 + 1];                           \
        acc[b][0] += (gi0.x * gj0.x - gi0.y * gj0.y) * pr00 +                \
                     (gi0.x * gj0.y + gi0.y * gj0.x) * pi00;                 \
        acc[b][1] += (gi0.x * gj1.x - gi0.y * gj1.y) * pr01 +                \
                     (gi0.x * gj1.y + gi0.y * gj1.x) * pi01;                 \
        acc[b][2] += (gi1.x * gj0.x - gi1.y * gj0.y) * pr10 +                \
                     (gi1.x * gj0.y + gi1.y * gj0.x) * pi10;                 \
        acc[b][3] += (gi1.x * gj1.x - gi1.y * gj1.y) * pr11 +                \
                     (gi1.x * gj1.y + gi1.y * gj1.x) * pi11;                 \
      }                                                                      \
    }

  #pragma unroll 1
  for (int cc = 0; cc < 16; cc += 4) {
    K6_STEP(pa0, pb0, cc + 0, cc + 4)
    K6_STEP(pa1, pb1, cc + 1, cc + 5)
    K6_STEP(pa2, pb2, cc + 2, cc + 6)
    K6_STEP(pa3, pb3, cc + 3, cc + 7)
  }
#undef K6_STEP

  #pragma unroll
  for (int b = 0; b < 4; ++b) {
    #pragma unroll
    for (int hh = 0; hh < 2; ++hh) {
      int h = h0 + th * 2 + hh;
      f2 st;
      st.x = acc[b][hh * 2 + 0];
      st.y = acc[b][hh * 2 + 1];
      __builtin_nontemporal_store(st,
          (f2*)(out + (((size_t)b * 768 + h) * 384 + (w0 >> 1) + tw) * 2));
    }
  }
}

extern "C" void kernel_launch(void* const* d_in, const int* in_sizes, int n_in,
                              void* d_out, int out_size, void* d_ws, size_t ws_size,
                              hipStream_t stream) {
  (void)in_sizes; (void)n_in; (void)out_size; (void)ws_size;
  const float* x    = (const float*)d_in[0];
  const float* Wc   = (const float*)d_in[1];
  const float* bc   = (const float*)d_in[2];
  const float* spi  = (const float*)d_in[3];
  const float* spj  = (const float*)d_in[4];
  const float* invs = (const float*)d_in[5];
  const float* GR   = (const float*)d_in[6];
  const float* GIm  = (const float*)d_in[7];
  const float* wm   = (const float*)d_in[8];
  const float* proj = (const float*)d_in[9];
  float* out = (float*)d_out;
  float* ws  = (float*)d_ws;

  n1_xm        <<<256, 256, 0, stream>>>(x, Wc, bc, ws + OFF_XR, ws + OFF_XI);
  n2_trans_beta<<<NT * 16 + 64, 256, 0, stream>>>(GR, GIm, ws + OFF_XR, ws + OFF_XI,
                                                  wm, ws + OFF_TR, ws + OFF_BE);
  k5_g         <<<dim3(16, 4, 6), 256, 0, stream>>>(spi, spj, invs, ws + OFF_TR,
                                                    ws + OFF_BE, ws + OFF_GI, ws + OFF_GJ);
  k6_out       <<<dim3(24, 24), 256, 0, stream>>>(proj, ws + OFF_GI, ws + OFF_GJ, out);
}

// Round 12
// 44.245 us; speedup vs baseline: 1.0027x; 1.0027x over previous
//
#include <hip/hip_runtime.h>
#include <math.h>

#define NCTX 2048
#define NT 34

typedef float f4 __attribute__((ext_vector_type(4)));
typedef float f2 __attribute__((ext_vector_type(2)));

// workspace float offsets
#define OFF_XR 0u         // 4*256
#define OFF_XI 1024u      // 4*256
#define OFF_TR 2048u      // 4*34*16*16*2 = 69632
#define OFF_BE 71680u     // 4*16*16 = 1024
#define OFF_GI 72704u     // 4*16*768*2 = 98304
#define OFF_GJ 171008u    // 4*16*768*2 = 98304

__device__ __forceinline__ float siglog(float v) {
  return copysignf(log1pf(fabsf(v)), v);
}

__device__ __forceinline__ f4 ntload4(const float* p) {
  return __builtin_nontemporal_load((const f4*)p);
}

// N1: paired GEMV rows (p, p+512) + siglog mix -> write xr/xi directly.
__global__ __launch_bounds__(256) void n1_xm(const float* __restrict__ x,
                                             const float* __restrict__ Wc,
                                             const float* __restrict__ bc,
                                             float* __restrict__ xr,
                                             float* __restrict__ xi) {
  const int p = blockIdx.x;  // 0..511
  const int tid = threadIdx.x;
  const float* w1 = Wc + (size_t)p * NCTX;
  const float* w2 = Wc + (size_t)(p + 512) * NCTX;
  const f4* x4 = (const f4*)x;
  float a00 = 0.f, a01 = 0.f, a02 = 0.f, a03 = 0.f;
  float a10 = 0.f, a11 = 0.f, a12 = 0.f, a13 = 0.f;
  #pragma unroll
  for (int it = 0; it < 2; ++it) {
    int i = tid + it * 256;
    f4 wa = ntload4(w1 + i * 4);
    f4 wb = ntload4(w2 + i * 4);
    f4 v0 = x4[i];
    f4 v1 = x4[512 + i];
    f4 v2 = x4[1024 + i];
    f4 v3 = x4[1536 + i];
    a00 += wa.x * v0.x + wa.y * v0.y + wa.z * v0.z + wa.w * v0.w;
    a01 += wa.x * v1.x + wa.y * v1.y + wa.z * v1.z + wa.w * v1.w;
    a02 += wa.x * v2.x + wa.y * v2.y + wa.z * v2.z + wa.w * v2.w;
    a03 += wa.x * v3.x + wa.y * v3.y + wa.z * v3.z + wa.w * v3.w;
    a10 += wb.x * v0.x + wb.y * v0.y + wb.z * v0.z + wb.w * v0.w;
    a11 += wb.x * v1.x + wb.y * v1.y + wb.z * v1.z + wb.w * v1.w;
    a12 += wb.x * v2.x + wb.y * v2.y + wb.z * v2.z + wb.w * v2.w;
    a13 += wb.x * v3.x + wb.y * v3.y + wb.z * v3.z + wb.w * v3.w;
  }
  __shared__ float red[8][256];
  __shared__ float sums[8];
  red[0][tid] = a00; red[1][tid] = a01; red[2][tid] = a02; red[3][tid] = a03;
  red[4][tid] = a10; red[5][tid] = a11; red[6][tid] = a12; red[7][tid] = a13;
  __syncthreads();
  const int wv = tid >> 6, lane = tid & 63;
  #pragma unroll
  for (int q = 0; q < 2; ++q) {
    int combo = wv * 2 + q;
    float s = red[combo][lane] + red[combo][lane + 64] +
              red[combo][lane + 128] + red[combo][lane + 192];
    #pragma unroll
    for (int off = 32; off > 0; off >>= 1) s += __shfl_down(s, off, 64);
    if (lane == 0) sums[combo] = s;
  }
  __syncthreads();
  if (tid < 4) {
    float d1 = sums[tid] + bc[p];
    float d2 = sums[4 + tid] + bc[p + 512];
    float v = d1 * siglog(d2);
    float* dst = (p & 1) ? xi : xr;
    dst[tid * 256 + (p >> 1)] = v;
  }
}

// N2: blocks 0..543 = trans einsum tiles (t,c); blocks 544..607 = beta (b,n).
__global__ __launch_bounds__(256) void n2_trans_beta(
    const float* __restrict__ GR, const float* __restrict__ GIm,
    const float* __restrict__ xr, const float* __restrict__ xi,
    const float* __restrict__ wm, float* __restrict__ tr,
    float* __restrict__ beta) {
  const int u = blockIdx.x;
  const int tid = threadIdx.x;
  __shared__ __align__(16) float smem[10880];
  if (u < NT * 16) {
    const int t = u >> 4;
    const int c = u & 15;
    float* grT = smem;            // [16][260]
    float* giT = smem + 4160;     // [16][260]
    float* xr_s = smem + 8320;    // [1024]
    float* xi_s = smem + 9344;    // [1024]
    f2* red2 = (f2*)(smem + 10368);  // [4][64]
    const float* grp = GR + (size_t)(t * 16 + c) * 4096;
    const float* gip = GIm + (size_t)(t * 16 + c) * 4096;
    #pragma unroll
    for (int it = 0; it < 4; ++it) {
      int k = tid + it * 256;          // float4 index over [l][r]
      int l = k >> 2, q = (k & 3) * 4; // r-start
      f4 g = ntload4(grp + k * 4);
      grT[(q + 0) * 260 + l] = g.x; grT[(q + 1) * 260 + l] = g.y;
      grT[(q + 2) * 260 + l] = g.z; grT[(q + 3) * 260 + l] = g.w;
      f4 h = ntload4(gip + k * 4);
      giT[(q + 0) * 260 + l] = h.x; giT[(q + 1) * 260 + l] = h.y;
      giT[(q + 2) * 260 + l] = h.z; giT[(q + 3) * 260 + l] = h.w;
    }
    ((f4*)xr_s)[tid] = ((const f4*)xr)[tid];
    ((f4*)xi_s)[tid] = ((const f4*)xi)[tid];
    __syncthreads();
    const int r = tid & 15, b = (tid >> 4) & 3, lseg = tid >> 6;
    const f4* grv = (const f4*)&grT[r * 260 + lseg * 64];
    const f4* giv = (const f4*)&giT[r * 260 + lseg * 64];
    const f4* xrv = (const f4*)&xr_s[b * 256 + lseg * 64];
    const f4* xiv = (const f4*)&xi_s[b * 256 + lseg * 64];
    float are = 0.f, aim = 0.f;
    #pragma unroll
    for (int li = 0; li < 16; ++li) {
      f4 g = grv[li], gg = giv[li], vr = xrv[li], vi = xiv[li];
      are += vr.x * g.x - vi.x * gg.x;  aim += vr.x * gg.x + vi.x * g.x;
      are += vr.y * g.y - vi.y * gg.y;  aim += vr.y * gg.y + vi.y * g.y;
      are += vr.z * g.z - vi.z * gg.z;  aim += vr.z * gg.z + vi.z * g.z;
      are += vr.w * g.w - vi.w * gg.w;  aim += vr.w * gg.w + vi.w * g.w;
    }
    f2 rv; rv.x = are; rv.y = aim;
    red2[lseg * 64 + b * 16 + r] = rv;
    __syncthreads();
    if (tid < 64) {
      const int rr = tid & 15, bb = tid >> 4;
      f2 s0 = red2[0 * 64 + tid], s1 = red2[1 * 64 + tid];
      f2 s2 = red2[2 * 64 + tid], s3 = red2[3 * 64 + tid];
      float sre = s0.x + s1.x + s2.x + s3.x;
      float sim = s0.y + s1.y + s2.y + s3.y;
      float mag = sqrtf(sre * sre + sim * sim + 1e-12f);
      float scale = 256.f * mag / (256.f * mag + 1e-12f);
      size_t o = ((((size_t)bb * NT + t) * 16 + c) * 16 + rr) * 2;
      tr[o]     = sre * scale;
      tr[o + 1] = sim * scale;
    }
  } else {
    // beta block: (b, n)
    const int u2 = u - NT * 16;
    const int n = u2 & 15, b = u2 >> 4;
    float* xr_s = smem;            // 256
    float* xi_s = smem + 256;      // 256
    f2* redb = (f2*)(smem + 512);  // [16][16]
    xr_s[tid] = xr[b * 256 + tid];
    xi_s[tid] = xi[b * 256 + tid];
    __syncthreads();
    const int r = tid & 15, lseg = tid >> 4;
    const f2* wm2 = (const f2*)wm;
    float tre = 0.f, tim = 0.f;
    #pragma unroll
    for (int li = 0; li < 16; ++li) {
      int l = lseg * 16 + li;
      f2 w = wm2[(size_t)l * 256 + n * 16 + r];
      float vr = xr_s[l], vi = xi_s[l];
      tre += vr * w.x - vi * w.y;
      tim += vr * w.y + vi * w.x;
    }
    f2 rv; rv.x = tre; rv.y = tim;
    redb[lseg * 16 + r] = rv;
    __syncthreads();
    if (tid < 16) {
      float sr = 0.f, si = 0.f;
      #pragma unroll
      for (int s = 0; s < 16; ++s) { sr += redb[s * 16 + tid].x; si += redb[s * 16 + tid].y; }
      float val = sqrtf(sr * sr + si * si + 1e-12f);
      float m = val;
      #pragma unroll
      for (int off = 8; off > 0; off >>= 1) m = fmaxf(m, __shfl_xor(m, off, 16));
      float e = expf(val - m);
      float ss = e;
      #pragma unroll
      for (int off = 8; off > 0; off >>= 1) ss += __shfl_xor(ss, off, 16);
      beta[(b * 16 + n) * 16 + tid] = e / ss;
    }
  }
}

// N3 (k5): build si/sj, apply inv, beta-weighted r-sum.
// grid (c=16, b=4, z=6): which = z/3, h-segment = z%3; one h per thread.
__global__ __launch_bounds__(256) void k5_g(const float* __restrict__ space_i,
                                            const float* __restrict__ space_j,
                                            const float* __restrict__ invs,
                                            const float* __restrict__ tr,
                                            const float* __restrict__ beta,
                                            float* __restrict__ gI,
                                            float* __restrict__ gJ) {
  const int c = blockIdx.x, b = blockIdx.y;
  const int which = blockIdx.z / 3, seg = blockIdx.z % 3;
  const int tid = threadIdx.x;
  __shared__ float sh_beta[16];
  __shared__ float sh_shift[16][2];
  __shared__ float sh_z[16][16][2];  // [rt][r][comp]
  if (tid < 16) sh_beta[tid] = beta[(b * 16 + c) * 16 + tid];
  if (tid >= 32 && tid < 64) {
    int t2 = tid - 32;
    int r = t2 >> 1, comp = t2 & 1;
    sh_shift[r][comp] = tr[((((size_t)b * NT + which) * 16 + c) * 16 + r) * 2 + comp];
  }
  for (int idx = tid; idx < 512; idx += 256) {
    int rt = idx >> 5, r = (idx >> 1) & 15, comp = idx & 1;
    int t = 2 + which * 16 + rt;
    sh_z[rt][r][comp] = tr[((((size_t)b * NT + t) * 16 + c) * 16 + r) * 2 + comp];
  }
  const float inv_re = invs[c * 2], inv_im = invs[c * 2 + 1];
  __syncthreads();
  const f2* sp2 = (const f2*)(which == 0 ? space_i : space_j);
  sp2 += (size_t)c * 16 * 768;
  f2* gout = (f2*)(which == 0 ? gI : gJ);
  gout += (size_t)(b * 16 + c) * 768;
  const int h = seg * 256 + tid;
  float pos = ((float)h + 0.5f) * (16.f / 768.f) - 0.5f;
  pos = fminf(fmaxf(pos, 0.f), 15.f);
  int lo = (int)floorf(pos);
  int hi = min(lo + 1, 15);
  float w = pos - (float)lo;
  float accR = 0.f, accI = 0.f;
  #pragma unroll
  for (int r = 0; r < 16; ++r) {
    f2 sp = sp2[r * 768 + h];
    float spr = sp.x + sh_shift[r][0];
    float spi = sp.y + sh_shift[r][1];
    float ztr = sh_z[lo][r][0] * (1.f - w) + sh_z[hi][r][0] * w;
    float zti = sh_z[lo][r][1] * (1.f - w) + sh_z[hi][r][1] * w;
    float sre = spr * ztr - spi * zti;
    float sim = spr * zti + spi * ztr;
    float br = sh_beta[r];
    if (which == 0) {
      accR += br * sre;
      accI += br * sim;
    } else {
      float den = fmaxf(sre * sre + sim * sim, 1e-4f);
      float id = 1.f / den;
      accR += br * (inv_re * sre + inv_im * sim) * id;
      accI += br * (inv_im * sre - inv_re * sim) * id;
    }
  }
  f2 o;
  if (which == 0) {  // gI = cmul(sum, inv)  (cmul linear in first arg)
    o.x = accR * inv_re - accI * inv_im;
    o.y = accR * inv_im + accI * inv_re;
  } else {
    o.x = accR; o.y = accI;
  }
  gout[h] = o;
}

// N4 (k6): out[b][h][w] = sum_c (wRe*pc + wIm*ps). 32x32 tile, 2x2/thread,
// depth-4 prefetch with NAMED registers (indexed arrays go to scratch).
__global__ __launch_bounds__(256) void k6_out(const float* __restrict__ proj,
                                              const float* __restrict__ gI,
                                              const float* __restrict__ gJ,
                                              float* __restrict__ out) {
  const int w0 = blockIdx.x * 32;
  const int h0 = blockIdx.y * 32;
  const int tid = threadIdx.x;
  const int tw = tid & 15, th = tid >> 4;
  __shared__ f2 gIs[64][32];  // [b*16+c][hh]
  __shared__ f2 gJs[64][32];  // [b*16+c][ww]
  const f2* gI2 = (const f2*)gI;
  const f2* gJ2 = (const f2*)gJ;
  #pragma unroll
  for (int it = 0; it < 8; ++it) {
    int idx = tid + it * 256;
    int i = idx & 31, bcp = idx >> 5;
    gIs[bcp][i] = gI2[(size_t)bcp * 768 + h0 + i];
    gJs[bcp][i] = gJ2[(size_t)bcp * 768 + w0 + i];
  }
  __syncthreads();
  const float* pp = proj + ((size_t)(h0 + th * 2) * 384 + (w0 >> 1) + tw) * 4;
  float acc[4][4];
  #pragma unroll
  for (int b = 0; b < 4; ++b)
    #pragma unroll
    for (int q = 0; q < 4; ++q) acc[b][q] = 0.f;

  const size_t CS = (size_t)768 * 384 * 4;
  f4 pa0 = ntload4(pp);
  f4 pb0 = ntload4(pp + 384 * 4);
  f4 pa1 = ntload4(pp + CS);
  f4 pb1 = ntload4(pp + CS + 384 * 4);
  f4 pa2 = ntload4(pp + 2 * CS);
  f4 pb2 = ntload4(pp + 2 * CS + 384 * 4);
  f4 pa3 = ntload4(pp + 3 * CS);
  f4 pb3 = ntload4(pp + 3 * CS + 384 * 4);

#define K6_STEP(PA, PB, CCUR, CNEXT)                                         \
    {                                                                        \
      f4 c0 = PA, c1 = PB;                                                   \
      if ((CNEXT) < 16) {                                                    \
        size_t nxt = (size_t)(CNEXT) * CS;                                   \
        PA = ntload4(pp + nxt);                                              \
        PB = ntload4(pp + nxt + 384 * 4);                                    \
      }                                                                      \
      float rq00 = rsqrtf(c0.x * c0.x + c0.y * c0.y + 1e-12f);               \
      float rq01 = rsqrtf(c0.z * c0.z + c0.w * c0.w + 1e-12f);               \
      float rq10 = rsqrtf(c1.x * c1.x + c1.y * c1.y + 1e-12f);               \
      float rq11 = rsqrtf(c1.z * c1.z + c1.w * c1.w + 1e-12f);               \
      float pr00 = c0.x * rq00, pi00 = c0.y * rq00;                          \
      float pr01 = c0.z * rq01, pi01 = c0.w * rq01;                          \
      float pr10 = c1.x * rq10, pi10 = c1.y * rq10;                          \
      float pr11 = c1.z * rq11, pi11 = c1.w * rq11;                          \
      _Pragma("unroll")                                                      \
      for (int b = 0; b < 4; ++b) {                                          \
        f2 gi0 = gIs[b * 16 + (CCUR)][th * 2];                               \
        f2 gi1 = gIs[b * 16 + (CCUR)][th * 2 + 1];                           \
        f2 gj0 = gJs[b * 16 + (CCUR)][tw * 2];                               \
        f2 gj1 = gJs[b * 16 + (CCUR)][tw * 2 + 1];                           \
        acc[b][0] += (gi0.x * gj0.x - gi0.y * gj0.y) * pr00 +                \
                     (gi0.x * gj0.y + gi0.y * gj0.x) * pi00;                 \
        acc[b][1] += (gi0.x * gj1.x - gi0.y * gj1.y) * pr01 +                \
                     (gi0.x * gj1.y + gi0.y * gj1.x) * pi01;                 \
        acc[b][2] += (gi1.x * gj0.x - gi1.y * gj0.y) * pr10 +                \
                     (gi1.x * gj0.y + gi1.y * gj0.x) * pi10;                 \
        acc[b][3] += (gi1.x * gj1.x - gi1.y * gj1.y) * pr11 +                \
                     (gi1.x * gj1.y + gi1.y * gj1.x) * pi11;                 \
      }                                                                      \
    }

  #pragma unroll 1
  for (int cc = 0; cc < 16; cc += 4) {
    K6_STEP(pa0, pb0, cc + 0, cc + 4)
    K6_STEP(pa1, pb1, cc + 1, cc + 5)
    K6_STEP(pa2, pb2, cc + 2, cc + 6)
    K6_STEP(pa3, pb3, cc + 3, cc + 7)
  }
#undef K6_STEP

  #pragma unroll
  for (int b = 0; b < 4; ++b) {
    #pragma unroll
    for (int hh = 0; hh < 2; ++hh) {
      int h = h0 + th * 2 + hh;
      f2 st;
      st.x = acc[b][hh * 2 + 0];
      st.y = acc[b][hh * 2 + 1];
      __builtin_nontemporal_store(st,
          (f2*)(out + (((size_t)b * 768 + h) * 384 + (w0 >> 1) + tw) * 2));
    }
  }
}

extern "C" void kernel_launch(void* const* d_in, const int* in_sizes, int n_in,
                              void* d_out, int out_size, void* d_ws, size_t ws_size,
                              hipStream_t stream) {
  (void)in_sizes; (void)n_in; (void)out_size; (void)ws_size;
  const float* x    = (const float*)d_in[0];
  const float* Wc   = (const float*)d_in[1];
  const float* bc   = (const float*)d_in[2];
  const float* spi  = (const float*)d_in[3];
  const float* spj  = (const float*)d_in[4];
  const float* invs = (const float*)d_in[5];
  const float* GR   = (const float*)d_in[6];
  const float* GIm  = (const float*)d_in[7];
  const float* wm   = (const float*)d_in[8];
  const float* proj = (const float*)d_in[9];
  float* out = (float*)d_out;
  float* ws  = (float*)d_ws;

  n1_xm        <<<512, 256, 0, stream>>>(x, Wc, bc, ws + OFF_XR, ws + OFF_XI);
  n2_trans_beta<<<NT * 16 + 64, 256, 0, stream>>>(GR, GIm, ws + OFF_XR, ws + OFF_XI,
                                                  wm, ws + OFF_TR, ws + OFF_BE);
  k5_g         <<<dim3(16, 4, 6), 256, 0, stream>>>(spi, spj, invs, ws + OFF_TR,
                                                    ws + OFF_BE, ws + OFF_GI, ws + OFF_GJ);
  k6_out       <<<dim3(24, 24), 256, 0, stream>>>(proj, ws + OFF_GI, ws + OFF_GJ, out);
}

// Round 13
// 42.460 us; speedup vs baseline: 1.0448x; 1.0420x over previous
//
#include <hip/hip_runtime.h>
#include <math.h>

#define NCTX 2048
#define NT 34

typedef float f4 __attribute__((ext_vector_type(4)));
typedef float f2 __attribute__((ext_vector_type(2)));

// workspace float offsets
#define OFF_XR 0u         // 4*256
#define OFF_XI 1024u      // 4*256
#define OFF_TR 2048u      // 4*34*16*16*2 = 69632
#define OFF_BE 71680u     // 4*16*16 = 1024
#define OFF_GI 72704u     // 4*16*768*2 = 98304
#define OFF_GJ 171008u    // 4*16*768*2 = 98304

__device__ __forceinline__ float siglog(float v) {
  return copysignf(log1pf(fabsf(v)), v);
}

__device__ __forceinline__ f4 ntload4(const float* p) {
  return __builtin_nontemporal_load((const f4*)p);
}

// N1: paired GEMV rows (p, p+512) + siglog mix -> write xr/xi directly.
__global__ __launch_bounds__(256) void n1_xm(const float* __restrict__ x,
                                             const float* __restrict__ Wc,
                                             const float* __restrict__ bc,
                                             float* __restrict__ xr,
                                             float* __restrict__ xi) {
  const int p = blockIdx.x;  // 0..511
  const int tid = threadIdx.x;
  const float* w1 = Wc + (size_t)p * NCTX;
  const float* w2 = Wc + (size_t)(p + 512) * NCTX;
  const f4* x4 = (const f4*)x;
  float a00 = 0.f, a01 = 0.f, a02 = 0.f, a03 = 0.f;
  float a10 = 0.f, a11 = 0.f, a12 = 0.f, a13 = 0.f;
  #pragma unroll
  for (int it = 0; it < 2; ++it) {
    int i = tid + it * 256;
    f4 wa = ntload4(w1 + i * 4);
    f4 wb = ntload4(w2 + i * 4);
    f4 v0 = x4[i];
    f4 v1 = x4[512 + i];
    f4 v2 = x4[1024 + i];
    f4 v3 = x4[1536 + i];
    a00 += wa.x * v0.x + wa.y * v0.y + wa.z * v0.z + wa.w * v0.w;
    a01 += wa.x * v1.x + wa.y * v1.y + wa.z * v1.z + wa.w * v1.w;
    a02 += wa.x * v2.x + wa.y * v2.y + wa.z * v2.z + wa.w * v2.w;
    a03 += wa.x * v3.x + wa.y * v3.y + wa.z * v3.z + wa.w * v3.w;
    a10 += wb.x * v0.x + wb.y * v0.y + wb.z * v0.z + wb.w * v0.w;
    a11 += wb.x * v1.x + wb.y * v1.y + wb.z * v1.z + wb.w * v1.w;
    a12 += wb.x * v2.x + wb.y * v2.y + wb.z * v2.z + wb.w * v2.w;
    a13 += wb.x * v3.x + wb.y * v3.y + wb.z * v3.z + wb.w * v3.w;
  }
  __shared__ float red[8][256];
  __shared__ float sums[8];
  red[0][tid] = a00; red[1][tid] = a01; red[2][tid] = a02; red[3][tid] = a03;
  red[4][tid] = a10; red[5][tid] = a11; red[6][tid] = a12; red[7][tid] = a13;
  __syncthreads();
  const int wv = tid >> 6, lane = tid & 63;
  #pragma unroll
  for (int q = 0; q < 2; ++q) {
    int combo = wv * 2 + q;
    float s = red[combo][lane] + red[combo][lane + 64] +
              red[combo][lane + 128] + red[combo][lane + 192];
    #pragma unroll
    for (int off = 32; off > 0; off >>= 1) s += __shfl_down(s, off, 64);
    if (lane == 0) sums[combo] = s;
  }
  __syncthreads();
  if (tid < 4) {
    float d1 = sums[tid] + bc[p];
    float d2 = sums[4 + tid] + bc[p + 512];
    float v = d1 * siglog(d2);
    float* dst = (p & 1) ? xi : xr;
    dst[tid * 256 + (p >> 1)] = v;
  }
}

// N2: blocks 0..543 = trans einsum tiles (t,c); blocks 544..607 = beta (b,n).
__global__ __launch_bounds__(256) void n2_trans_beta(
    const float* __restrict__ GR, const float* __restrict__ GIm,
    const float* __restrict__ xr, const float* __restrict__ xi,
    const float* __restrict__ wm, float* __restrict__ tr,
    float* __restrict__ beta) {
  const int u = blockIdx.x;
  const int tid = threadIdx.x;
  __shared__ __align__(16) float smem[10880];
  if (u < NT * 16) {
    const int t = u >> 4;
    const int c = u & 15;
    float* grT = smem;            // [16][260]
    float* giT = smem + 4160;     // [16][260]
    float* xr_s = smem + 8320;    // [1024]
    float* xi_s = smem + 9344;    // [1024]
    f2* red2 = (f2*)(smem + 10368);  // [4][64]
    const float* grp = GR + (size_t)(t * 16 + c) * 4096;
    const float* gip = GIm + (size_t)(t * 16 + c) * 4096;
    #pragma unroll
    for (int it = 0; it < 4; ++it) {
      int k = tid + it * 256;          // float4 index over [l][r]
      int l = k >> 2, q = (k & 3) * 4; // r-start
      f4 g = ntload4(grp + k * 4);
      grT[(q + 0) * 260 + l] = g.x; grT[(q + 1) * 260 + l] = g.y;
      grT[(q + 2) * 260 + l] = g.z; grT[(q + 3) * 260 + l] = g.w;
      f4 h = ntload4(gip + k * 4);
      giT[(q + 0) * 260 + l] = h.x; giT[(q + 1) * 260 + l] = h.y;
      giT[(q + 2) * 260 + l] = h.z; giT[(q + 3) * 260 + l] = h.w;
    }
    ((f4*)xr_s)[tid] = ((const f4*)xr)[tid];
    ((f4*)xi_s)[tid] = ((const f4*)xi)[tid];
    __syncthreads();
    const int r = tid & 15, b = (tid >> 4) & 3, lseg = tid >> 6;
    const f4* grv = (const f4*)&grT[r * 260 + lseg * 64];
    const f4* giv = (const f4*)&giT[r * 260 + lseg * 64];
    const f4* xrv = (const f4*)&xr_s[b * 256 + lseg * 64];
    const f4* xiv = (const f4*)&xi_s[b * 256 + lseg * 64];
    float are = 0.f, aim = 0.f;
    #pragma unroll
    for (int li = 0; li < 16; ++li) {
      f4 g = grv[li], gg = giv[li], vr = xrv[li], vi = xiv[li];
      are += vr.x * g.x - vi.x * gg.x;  aim += vr.x * gg.x + vi.x * g.x;
      are += vr.y * g.y - vi.y * gg.y;  aim += vr.y * gg.y + vi.y * g.y;
      are += vr.z * g.z - vi.z * gg.z;  aim += vr.z * gg.z + vi.z * g.z;
      are += vr.w * g.w - vi.w * gg.w;  aim += vr.w * gg.w + vi.w * g.w;
    }
    f2 rv; rv.x = are; rv.y = aim;
    red2[lseg * 64 + b * 16 + r] = rv;
    __syncthreads();
    if (tid < 64) {
      const int rr = tid & 15, bb = tid >> 4;
      f2 s0 = red2[0 * 64 + tid], s1 = red2[1 * 64 + tid];
      f2 s2 = red2[2 * 64 + tid], s3 = red2[3 * 64 + tid];
      float sre = s0.x + s1.x + s2.x + s3.x;
      float sim = s0.y + s1.y + s2.y + s3.y;
      float mag = sqrtf(sre * sre + sim * sim + 1e-12f);
      float scale = 256.f * mag / (256.f * mag + 1e-12f);
      size_t o = ((((size_t)bb * NT + t) * 16 + c) * 16 + rr) * 2;
      tr[o]     = sre * scale;
      tr[o + 1] = sim * scale;
    }
  } else {
    // beta block: (b, n)
    const int u2 = u - NT * 16;
    const int n = u2 & 15, b = u2 >> 4;
    float* xr_s = smem;            // 256
    float* xi_s = smem + 256;      // 256
    f2* redb = (f2*)(smem + 512);  // [16][16]
    xr_s[tid] = xr[b * 256 + tid];
    xi_s[tid] = xi[b * 256 + tid];
    __syncthreads();
    const int r = tid & 15, lseg = tid >> 4;
    const f2* wm2 = (const f2*)wm;
    float tre = 0.f, tim = 0.f;
    #pragma unroll
    for (int li = 0; li < 16; ++li) {
      int l = lseg * 16 + li;
      f2 w = wm2[(size_t)l * 256 + n * 16 + r];
      float vr = xr_s[l], vi = xi_s[l];
      tre += vr * w.x - vi * w.y;
      tim += vr * w.y + vi * w.x;
    }
    f2 rv; rv.x = tre; rv.y = tim;
    redb[lseg * 16 + r] = rv;
    __syncthreads();
    if (tid < 16) {
      float sr = 0.f, si = 0.f;
      #pragma unroll
      for (int s = 0; s < 16; ++s) { sr += redb[s * 16 + tid].x; si += redb[s * 16 + tid].y; }
      float val = sqrtf(sr * sr + si * si + 1e-12f);
      float m = val;
      #pragma unroll
      for (int off = 8; off > 0; off >>= 1) m = fmaxf(m, __shfl_xor(m, off, 16));
      float e = expf(val - m);
      float ss = e;
      #pragma unroll
      for (int off = 8; off > 0; off >>= 1) ss += __shfl_xor(ss, off, 16);
      beta[(b * 16 + n) * 16 + tid] = e / ss;
    }
  }
}

// N3 (k5): build si/sj, apply inv, beta-weighted r-sum.
// grid (c=16, b=4, z=6): which = z/3, h-segment = z%3; one h per thread.
__global__ __launch_bounds__(256) void k5_g(const float* __restrict__ space_i,
                                            const float* __restrict__ space_j,
                                            const float* __restrict__ invs,
                                            const float* __restrict__ tr,
                                            const float* __restrict__ beta,
                                            float* __restrict__ gI,
                                            float* __restrict__ gJ) {
  const int c = blockIdx.x, b = blockIdx.y;
  const int which = blockIdx.z / 3, seg = blockIdx.z % 3;
  const int tid = threadIdx.x;
  __shared__ float sh_beta[16];
  __shared__ float sh_shift[16][2];
  __shared__ float sh_z[16][16][2];  // [rt][r][comp]
  if (tid < 16) sh_beta[tid] = beta[(b * 16 + c) * 16 + tid];
  if (tid >= 32 && tid < 64) {
    int t2 = tid - 32;
    int r = t2 >> 1, comp = t2 & 1;
    sh_shift[r][comp] = tr[((((size_t)b * NT + which) * 16 + c) * 16 + r) * 2 + comp];
  }
  for (int idx = tid; idx < 512; idx += 256) {
    int rt = idx >> 5, r = (idx >> 1) & 15, comp = idx & 1;
    int t = 2 + which * 16 + rt;
    sh_z[rt][r][comp] = tr[((((size_t)b * NT + t) * 16 + c) * 16 + r) * 2 + comp];
  }
  const float inv_re = invs[c * 2], inv_im = invs[c * 2 + 1];
  __syncthreads();
  const f2* sp2 = (const f2*)(which == 0 ? space_i : space_j);
  sp2 += (size_t)c * 16 * 768;
  f2* gout = (f2*)(which == 0 ? gI : gJ);
  gout += (size_t)(b * 16 + c) * 768;
  const int h = seg * 256 + tid;
  float pos = ((float)h + 0.5f) * (16.f / 768.f) - 0.5f;
  pos = fminf(fmaxf(pos, 0.f), 15.f);
  int lo = (int)floorf(pos);
  int hi = min(lo + 1, 15);
  float w = pos - (float)lo;
  float accR = 0.f, accI = 0.f;
  #pragma unroll
  for (int r = 0; r < 16; ++r) {
    f2 sp = sp2[r * 768 + h];
    float spr = sp.x + sh_shift[r][0];
    float spi = sp.y + sh_shift[r][1];
    float ztr = sh_z[lo][r][0] * (1.f - w) + sh_z[hi][r][0] * w;
    float zti = sh_z[lo][r][1] * (1.f - w) + sh_z[hi][r][1] * w;
    float sre = spr * ztr - spi * zti;
    float sim = spr * zti + spi * ztr;
    float br = sh_beta[r];
    if (which == 0) {
      accR += br * sre;
      accI += br * sim;
    } else {
      float den = fmaxf(sre * sre + sim * sim, 1e-4f);
      float id = 1.f / den;
      accR += br * (inv_re * sre + inv_im * sim) * id;
      accI += br * (inv_im * sre - inv_re * sim) * id;
    }
  }
  f2 o;
  if (which == 0) {  // gI = cmul(sum, inv)  (cmul linear in first arg)
    o.x = accR * inv_re - accI * inv_im;
    o.y = accR * inv_im + accI * inv_re;
  } else {
    o.x = accR; o.y = accI;
  }
  gout[h] = o;
}

// N4 (k6): out[b][h][w] = sum_c (wRe*pc + wIm*ps). 32x32 tile, 2x2/thread,
// depth-2 prefetch with NAMED registers (depth-4 measured -1.5us; arrays
// measured -8us; this exact form is the best-measured config).
__global__ __launch_bounds__(256) void k6_out(const float* __restrict__ proj,
                                              const float* __restrict__ gI,
                                              const float* __restrict__ gJ,
                                              float* __restrict__ out) {
  const int w0 = blockIdx.x * 32;
  const int h0 = blockIdx.y * 32;
  const int tid = threadIdx.x;
  const int tw = tid & 15, th = tid >> 4;
  __shared__ f2 gIs[64][32];  // [b*16+c][hh]
  __shared__ f2 gJs[64][32];  // [b*16+c][ww]
  const f2* gI2 = (const f2*)gI;
  const f2* gJ2 = (const f2*)gJ;
  #pragma unroll
  for (int it = 0; it < 8; ++it) {
    int idx = tid + it * 256;
    int i = idx & 31, bcp = idx >> 5;
    gIs[bcp][i] = gI2[(size_t)bcp * 768 + h0 + i];
    gJs[bcp][i] = gJ2[(size_t)bcp * 768 + w0 + i];
  }
  __syncthreads();
  const float* pp = proj + ((size_t)(h0 + th * 2) * 384 + (w0 >> 1) + tw) * 4;
  float acc[4][4];
  #pragma unroll
  for (int b = 0; b < 4; ++b)
    #pragma unroll
    for (int q = 0; q < 4; ++q) acc[b][q] = 0.f;

  f4 pa0 = ntload4(pp);
  f4 pb0 = ntload4(pp + 384 * 4);
  f4 pa1 = ntload4(pp + (size_t)768 * 384 * 4);
  f4 pb1 = ntload4(pp + (size_t)768 * 384 * 4 + 384 * 4);

#define K6_STEP(PA, PB, CCUR, CNEXT)                                         \
    {                                                                        \
      f4 c0 = PA, c1 = PB;                                                   \
      if ((CNEXT) < 16) {                                                    \
        size_t nxt = (size_t)(CNEXT) * 768 * 384 * 4;                        \
        PA = ntload4(pp + nxt);                                              \
        PB = ntload4(pp + nxt + 384 * 4);                                    \
      }                                                                      \
      float rq00 = rsqrtf(c0.x * c0.x + c0.y * c0.y + 1e-12f);               \
      float rq01 = rsqrtf(c0.z * c0.z + c0.w * c0.w + 1e-12f);               \
      float rq10 = rsqrtf(c1.x * c1.x + c1.y * c1.y + 1e-12f);               \
      float rq11 = rsqrtf(c1.z * c1.z + c1.w * c1.w + 1e-12f);               \
      float pr00 = c0.x * rq00, pi00 = c0.y * rq00;                          \
      float pr01 = c0.z * rq01, pi01 = c0.w * rq01;                          \
      float pr10 = c1.x * rq10, pi10 = c1.y * rq10;                          \
      float pr11 = c1.z * rq11, pi11 = c1.w * rq11;                          \
      _Pragma("unroll")                                                      \
      for (int b = 0; b < 4; ++b) {                                          \
        f2 gi0 = gIs[b * 16 + (CCUR)][th * 2];                               \
        f2 gi1 = gIs[b * 16 + (CCUR)][th * 2 + 1];                           \
        f2 gj0 = gJs[b * 16 + (CCUR)][tw * 2];                               \
        f2 gj1 = gJs[b * 16 + (CCUR)][tw * 2 + 1];                           \
        acc[b][0] += (gi0.x * gj0.x - gi0.y * gj0.y) * pr00 +                \
                     (gi0.x * gj0.y + gi0.y * gj0.x) * pi00;                 \
        acc[b][1] += (gi0.x * gj1.x - gi0.y * gj1.y) * pr01 +                \
                     (gi0.x * gj1.y + gi0.y * gj1.x) * pi01;                 \
        acc[b][2] += (gi1.x * gj0.x - gi1.y * gj0.y) * pr10 +                \
                     (gi1.x * gj0.y + gi1.y * gj0.x) * pi10;                 \
        acc[b][3] += (gi1.x * gj1.x - gi1.y * gj1.y) * pr11 +                \
                     (gi1.x * gj1.y + gi1.y * gj1.x) * pi11;                 \
      }                                                                      \
    }

  #pragma unroll 1
  for (int cc = 0; cc < 16; cc += 2) {
    K6_STEP(pa0, pb0, cc, cc + 2)
    K6_STEP(pa1, pb1, cc + 1, cc + 3)
  }
#undef K6_STEP

  #pragma unroll
  for (int b = 0; b < 4; ++b) {
    #pragma unroll
    for (int hh = 0; hh < 2; ++hh) {
      int h = h0 + th * 2 + hh;
      f2 st;
      st.x = acc[b][hh * 2 + 0];
      st.y = acc[b][hh * 2 + 1];
      __builtin_nontemporal_store(st,
          (f2*)(out + (((size_t)b * 768 + h) * 384 + (w0 >> 1) + tw) * 2));
    }
  }
}

extern "C" void kernel_launch(void* const* d_in, const int* in_sizes, int n_in,
                              void* d_out, int out_size, void* d_ws, size_t ws_size,
                              hipStream_t stream) {
  (void)in_sizes; (void)n_in; (void)out_size; (void)ws_size;
  const float* x    = (const float*)d_in[0];
  const float* Wc   = (const float*)d_in[1];
  const float* bc   = (const float*)d_in[2];
  const float* spi  = (const float*)d_in[3];
  const float* spj  = (const float*)d_in[4];
  const float* invs = (const float*)d_in[5];
  const float* GR   = (const float*)d_in[6];
  const float* GIm  = (const float*)d_in[7];
  const float* wm   = (const float*)d_in[8];
  const float* proj = (const float*)d_in[9];
  float* out = (float*)d_out;
  float* ws  = (float*)d_ws;

  n1_xm        <<<512, 256, 0, stream>>>(x, Wc, bc, ws + OFF_XR, ws + OFF_XI);
  n2_trans_beta<<<NT * 16 + 64, 256, 0, stream>>>(GR, GIm, ws + OFF_XR, ws + OFF_XI,
                                                  wm, ws + OFF_TR, ws + OFF_BE);
  k5_g         <<<dim3(16, 4, 6), 256, 0, stream>>>(spi, spj, invs, ws + OFF_TR,
                                                    ws + OFF_BE, ws + OFF_GI, ws + OFF_GJ);
  k6_out       <<<dim3(24, 24), 256, 0, stream>>>(proj, ws + OFF_GI, ws + OFF_GJ, out);
}

// Round 14
// 42.141 us; speedup vs baseline: 1.0528x; 1.0076x over previous
//
#include <hip/hip_runtime.h>
#include <math.h>

#define NCTX 2048
#define NT 34

typedef float f4 __attribute__((ext_vector_type(4)));
typedef float f2 __attribute__((ext_vector_type(2)));

// workspace float offsets
#define OFF_XR 0u         // 4*256
#define OFF_XI 1024u      // 4*256
#define OFF_TR 2048u      // 4*34*16*16*2 = 69632
#define OFF_BE 71680u     // 4*16*16 = 1024
#define OFF_GI 72704u     // 4*16*768*2 = 98304
#define OFF_GJ 171008u    // 4*16*768*2 = 98304

__device__ __forceinline__ float siglog(float v) {
  return copysignf(log1pf(fabsf(v)), v);
}

__device__ __forceinline__ f4 ntload4(const float* p) {
  return __builtin_nontemporal_load((const f4*)p);
}

// N1: paired GEMV rows (p, p+512) + siglog mix -> write xr/xi directly.
__global__ __launch_bounds__(256) void n1_xm(const float* __restrict__ x,
                                             const float* __restrict__ Wc,
                                             const float* __restrict__ bc,
                                             float* __restrict__ xr,
                                             float* __restrict__ xi) {
  const int p = blockIdx.x;  // 0..511
  const int tid = threadIdx.x;
  const float* w1 = Wc + (size_t)p * NCTX;
  const float* w2 = Wc + (size_t)(p + 512) * NCTX;
  const f4* x4 = (const f4*)x;
  float a00 = 0.f, a01 = 0.f, a02 = 0.f, a03 = 0.f;
  float a10 = 0.f, a11 = 0.f, a12 = 0.f, a13 = 0.f;
  #pragma unroll
  for (int it = 0; it < 2; ++it) {
    int i = tid + it * 256;
    f4 wa = ntload4(w1 + i * 4);
    f4 wb = ntload4(w2 + i * 4);
    f4 v0 = x4[i];
    f4 v1 = x4[512 + i];
    f4 v2 = x4[1024 + i];
    f4 v3 = x4[1536 + i];
    a00 += wa.x * v0.x + wa.y * v0.y + wa.z * v0.z + wa.w * v0.w;
    a01 += wa.x * v1.x + wa.y * v1.y + wa.z * v1.z + wa.w * v1.w;
    a02 += wa.x * v2.x + wa.y * v2.y + wa.z * v2.z + wa.w * v2.w;
    a03 += wa.x * v3.x + wa.y * v3.y + wa.z * v3.z + wa.w * v3.w;
    a10 += wb.x * v0.x + wb.y * v0.y + wb.z * v0.z + wb.w * v0.w;
    a11 += wb.x * v1.x + wb.y * v1.y + wb.z * v1.z + wb.w * v1.w;
    a12 += wb.x * v2.x + wb.y * v2.y + wb.z * v2.z + wb.w * v2.w;
    a13 += wb.x * v3.x + wb.y * v3.y + wb.z * v3.z + wb.w * v3.w;
  }
  __shared__ float red[8][256];
  __shared__ float sums[8];
  red[0][tid] = a00; red[1][tid] = a01; red[2][tid] = a02; red[3][tid] = a03;
  red[4][tid] = a10; red[5][tid] = a11; red[6][tid] = a12; red[7][tid] = a13;
  __syncthreads();
  const int wv = tid >> 6, lane = tid & 63;
  #pragma unroll
  for (int q = 0; q < 2; ++q) {
    int combo = wv * 2 + q;
    float s = red[combo][lane] + red[combo][lane + 64] +
              red[combo][lane + 128] + red[combo][lane + 192];
    #pragma unroll
    for (int off = 32; off > 0; off >>= 1) s += __shfl_down(s, off, 64);
    if (lane == 0) sums[combo] = s;
  }
  __syncthreads();
  if (tid < 4) {
    float d1 = sums[tid] + bc[p];
    float d2 = sums[4 + tid] + bc[p + 512];
    float v = d1 * siglog(d2);
    float* dst = (p & 1) ? xi : xr;
    dst[tid * 256 + (p >> 1)] = v;
  }
}

// N2: blocks 0..543 = trans einsum tiles (t,c); blocks 544..607 = beta (b,n).
__global__ __launch_bounds__(256) void n2_trans_beta(
    const float* __restrict__ GR, const float* __restrict__ GIm,
    const float* __restrict__ xr, const float* __restrict__ xi,
    const float* __restrict__ wm, float* __restrict__ tr,
    float* __restrict__ beta) {
  const int u = blockIdx.x;
  const int tid = threadIdx.x;
  __shared__ __align__(16) float smem[10880];
  if (u < NT * 16) {
    const int t = u >> 4;
    const int c = u & 15;
    float* grT = smem;            // [16][260]
    float* giT = smem + 4160;     // [16][260]
    float* xr_s = smem + 8320;    // [1024]
    float* xi_s = smem + 9344;    // [1024]
    f2* red2 = (f2*)(smem + 10368);  // [4][64]
    const float* grp = GR + (size_t)(t * 16 + c) * 4096;
    const float* gip = GIm + (size_t)(t * 16 + c) * 4096;
    #pragma unroll
    for (int it = 0; it < 4; ++it) {
      int k = tid + it * 256;          // float4 index over [l][r]
      int l = k >> 2, q = (k & 3) * 4; // r-start
      f4 g = ntload4(grp + k * 4);
      grT[(q + 0) * 260 + l] = g.x; grT[(q + 1) * 260 + l] = g.y;
      grT[(q + 2) * 260 + l] = g.z; grT[(q + 3) * 260 + l] = g.w;
      f4 h = ntload4(gip + k * 4);
      giT[(q + 0) * 260 + l] = h.x; giT[(q + 1) * 260 + l] = h.y;
      giT[(q + 2) * 260 + l] = h.z; giT[(q + 3) * 260 + l] = h.w;
    }
    ((f4*)xr_s)[tid] = ((const f4*)xr)[tid];
    ((f4*)xi_s)[tid] = ((const f4*)xi)[tid];
    __syncthreads();
    const int r = tid & 15, b = (tid >> 4) & 3, lseg = tid >> 6;
    const f4* grv = (const f4*)&grT[r * 260 + lseg * 64];
    const f4* giv = (const f4*)&giT[r * 260 + lseg * 64];
    const f4* xrv = (const f4*)&xr_s[b * 256 + lseg * 64];
    const f4* xiv = (const f4*)&xi_s[b * 256 + lseg * 64];
    float are = 0.f, aim = 0.f;
    #pragma unroll
    for (int li = 0; li < 16; ++li) {
      f4 g = grv[li], gg = giv[li], vr = xrv[li], vi = xiv[li];
      are += vr.x * g.x - vi.x * gg.x;  aim += vr.x * gg.x + vi.x * g.x;
      are += vr.y * g.y - vi.y * gg.y;  aim += vr.y * gg.y + vi.y * g.y;
      are += vr.z * g.z - vi.z * gg.z;  aim += vr.z * gg.z + vi.z * g.z;
      are += vr.w * g.w - vi.w * gg.w;  aim += vr.w * gg.w + vi.w * g.w;
    }
    f2 rv; rv.x = are; rv.y = aim;
    red2[lseg * 64 + b * 16 + r] = rv;
    __syncthreads();
    if (tid < 64) {
      const int rr = tid & 15, bb = tid >> 4;
      f2 s0 = red2[0 * 64 + tid], s1 = red2[1 * 64 + tid];
      f2 s2 = red2[2 * 64 + tid], s3 = red2[3 * 64 + tid];
      float sre = s0.x + s1.x + s2.x + s3.x;
      float sim = s0.y + s1.y + s2.y + s3.y;
      float mag = sqrtf(sre * sre + sim * sim + 1e-12f);
      float scale = 256.f * mag / (256.f * mag + 1e-12f);
      size_t o = ((((size_t)bb * NT + t) * 16 + c) * 16 + rr) * 2;
      tr[o]     = sre * scale;
      tr[o + 1] = sim * scale;
    }
  } else {
    // beta block: (b, n)
    const int u2 = u - NT * 16;
    const int n = u2 & 15, b = u2 >> 4;
    float* xr_s = smem;            // 256
    float* xi_s = smem + 256;      // 256
    f2* redb = (f2*)(smem + 512);  // [16][16]
    xr_s[tid] = xr[b * 256 + tid];
    xi_s[tid] = xi[b * 256 + tid];
    __syncthreads();
    const int r = tid & 15, lseg = tid >> 4;
    const f2* wm2 = (const f2*)wm;
    float tre = 0.f, tim = 0.f;
    #pragma unroll
    for (int li = 0; li < 16; ++li) {
      int l = lseg * 16 + li;
      f2 w = wm2[(size_t)l * 256 + n * 16 + r];
      float vr = xr_s[l], vi = xi_s[l];
      tre += vr * w.x - vi * w.y;
      tim += vr * w.y + vi * w.x;
    }
    f2 rv; rv.x = tre; rv.y = tim;
    redb[lseg * 16 + r] = rv;
    __syncthreads();
    if (tid < 16) {
      float sr = 0.f, si = 0.f;
      #pragma unroll
      for (int s = 0; s < 16; ++s) { sr += redb[s * 16 + tid].x; si += redb[s * 16 + tid].y; }
      float val = sqrtf(sr * sr + si * si + 1e-12f);
      float m = val;
      #pragma unroll
      for (int off = 8; off > 0; off >>= 1) m = fmaxf(m, __shfl_xor(m, off, 16));
      float e = expf(val - m);
      float ss = e;
      #pragma unroll
      for (int off = 8; off > 0; off >>= 1) ss += __shfl_xor(ss, off, 16);
      beta[(b * 16 + n) * 16 + tid] = e / ss;
    }
  }
}

// N3 (k5): build si/sj, apply inv, beta-weighted r-sum.
// grid (c=16, b=4, z=6): which = z/3, h-segment = z%3; one h per thread.
__global__ __launch_bounds__(256) void k5_g(const float* __restrict__ space_i,
                                            const float* __restrict__ space_j,
                                            const float* __restrict__ invs,
                                            const float* __restrict__ tr,
                                            const float* __restrict__ beta,
                                            float* __restrict__ gI,
                                            float* __restrict__ gJ) {
  const int c = blockIdx.x, b = blockIdx.y;
  const int which = blockIdx.z / 3, seg = blockIdx.z % 3;
  const int tid = threadIdx.x;
  __shared__ float sh_beta[16];
  __shared__ float sh_shift[16][2];
  __shared__ float sh_z[16][16][2];  // [rt][r][comp]
  if (tid < 16) sh_beta[tid] = beta[(b * 16 + c) * 16 + tid];
  if (tid >= 32 && tid < 64) {
    int t2 = tid - 32;
    int r = t2 >> 1, comp = t2 & 1;
    sh_shift[r][comp] = tr[((((size_t)b * NT + which) * 16 + c) * 16 + r) * 2 + comp];
  }
  for (int idx = tid; idx < 512; idx += 256) {
    int rt = idx >> 5, r = (idx >> 1) & 15, comp = idx & 1;
    int t = 2 + which * 16 + rt;
    sh_z[rt][r][comp] = tr[((((size_t)b * NT + t) * 16 + c) * 16 + r) * 2 + comp];
  }
  const float inv_re = invs[c * 2], inv_im = invs[c * 2 + 1];
  __syncthreads();
  const f2* sp2 = (const f2*)(which == 0 ? space_i : space_j);
  sp2 += (size_t)c * 16 * 768;
  f2* gout = (f2*)(which == 0 ? gI : gJ);
  gout += (size_t)(b * 16 + c) * 768;
  const int h = seg * 256 + tid;
  float pos = ((float)h + 0.5f) * (16.f / 768.f) - 0.5f;
  pos = fminf(fmaxf(pos, 0.f), 15.f);
  int lo = (int)floorf(pos);
  int hi = min(lo + 1, 15);
  float w = pos - (float)lo;
  float accR = 0.f, accI = 0.f;
  #pragma unroll
  for (int r = 0; r < 16; ++r) {
    f2 sp = sp2[r * 768 + h];
    float spr = sp.x + sh_shift[r][0];
    float spi = sp.y + sh_shift[r][1];
    float ztr = sh_z[lo][r][0] * (1.f - w) + sh_z[hi][r][0] * w;
    float zti = sh_z[lo][r][1] * (1.f - w) + sh_z[hi][r][1] * w;
    float sre = spr * ztr - spi * zti;
    float sim = spr * zti + spi * ztr;
    float br = sh_beta[r];
    if (which == 0) {
      accR += br * sre;
      accI += br * sim;
    } else {
      float den = fmaxf(sre * sre + sim * sim, 1e-4f);
      float id = 1.f / den;
      accR += br * (inv_re * sre + inv_im * sim) * id;
      accI += br * (inv_im * sre - inv_re * sim) * id;
    }
  }
  f2 o;
  if (which == 0) {  // gI = cmul(sum, inv)  (cmul linear in first arg)
    o.x = accR * inv_re - accI * inv_im;
    o.y = accR * inv_im + accI * inv_re;
  } else {
    o.x = accR; o.y = accI;
  }
  gout[h] = o;
}

// N4 (k6): out[b][h][w] = sum_c (wRe*pc + wIm*ps). 16h x 32w tile (1152
// blocks = 4.5/CU, imbalance 1.11x vs 1.33x at 576), 1x2 outputs/thread x 4b,
// depth-2 prefetch with NAMED registers.
__global__ __launch_bounds__(256) void k6_out(const float* __restrict__ proj,
                                              const float* __restrict__ gI,
                                              const float* __restrict__ gJ,
                                              float* __restrict__ out) {
  const int w0 = blockIdx.x * 32;
  const int h0 = blockIdx.y * 16;
  const int tid = threadIdx.x;
  const int tw = tid & 15, th = tid >> 4;
  __shared__ f2 gIs[64][16];  // [b*16+c][hh]
  __shared__ f2 gJs[64][32];  // [b*16+c][ww]
  const f2* gI2 = (const f2*)gI;
  const f2* gJ2 = (const f2*)gJ;
  #pragma unroll
  for (int it = 0; it < 4; ++it) {  // 1024 gIs entries
    int idx = tid + it * 256;
    gIs[idx >> 4][idx & 15] = gI2[(size_t)(idx >> 4) * 768 + h0 + (idx & 15)];
  }
  #pragma unroll
  for (int it = 0; it < 8; ++it) {  // 2048 gJs entries
    int idx = tid + it * 256;
    gJs[idx >> 5][idx & 31] = gJ2[(size_t)(idx >> 5) * 768 + w0 + (idx & 31)];
  }
  __syncthreads();
  const int h = h0 + th;
  const float* pp = proj + ((size_t)h * 384 + (w0 >> 1) + tw) * 4;
  const size_t CS = (size_t)768 * 384 * 4;
  float acc[4][2];
  #pragma unroll
  for (int b = 0; b < 4; ++b) { acc[b][0] = 0.f; acc[b][1] = 0.f; }

  f4 pa0 = ntload4(pp);
  f4 pa1 = ntload4(pp + CS);

#define K6_STEP(PA, CCUR, CNEXT)                                             \
    {                                                                        \
      f4 c0 = PA;                                                            \
      if ((CNEXT) < 16) {                                                    \
        PA = ntload4(pp + (size_t)(CNEXT) * CS);                             \
      }                                                                      \
      float rq0 = rsqrtf(c0.x * c0.x + c0.y * c0.y + 1e-12f);                \
      float rq1 = rsqrtf(c0.z * c0.z + c0.w * c0.w + 1e-12f);                \
      float pr0 = c0.x * rq0, pi0 = c0.y * rq0;                              \
      float pr1 = c0.z * rq1, pi1 = c0.w * rq1;                              \
      _Pragma("unroll")                                                      \
      for (int b = 0; b < 4; ++b) {                                          \
        f2 gi = gIs[b * 16 + (CCUR)][th];                                    \
        f2 gj0 = gJs[b * 16 + (CCUR)][tw * 2];                               \
        f2 gj1 = gJs[b * 16 + (CCUR)][tw * 2 + 1];                           \
        acc[b][0] += (gi.x * gj0.x - gi.y * gj0.y) * pr0 +                   \
                     (gi.x * gj0.y + gi.y * gj0.x) * pi0;                    \
        acc[b][1] += (gi.x * gj1.x - gi.y * gj1.y) * pr1 +                   \
                     (gi.x * gj1.y + gi.y * gj1.x) * pi1;                    \
      }                                                                      \
    }

  #pragma unroll 1
  for (int cc = 0; cc < 16; cc += 2) {
    K6_STEP(pa0, cc, cc + 2)
    K6_STEP(pa1, cc + 1, cc + 3)
  }
#undef K6_STEP

  #pragma unroll
  for (int b = 0; b < 4; ++b) {
    f2 st;
    st.x = acc[b][0];
    st.y = acc[b][1];
    __builtin_nontemporal_store(st,
        (f2*)(out + (((size_t)b * 768 + h) * 384 + (w0 >> 1) + tw) * 2));
  }
}

extern "C" void kernel_launch(void* const* d_in, const int* in_sizes, int n_in,
                              void* d_out, int out_size, void* d_ws, size_t ws_size,
                              hipStream_t stream) {
  (void)in_sizes; (void)n_in; (void)out_size; (void)ws_size;
  const float* x    = (const float*)d_in[0];
  const float* Wc   = (const float*)d_in[1];
  const float* bc   = (const float*)d_in[2];
  const float* spi  = (const float*)d_in[3];
  const float* spj  = (const float*)d_in[4];
  const float* invs = (const float*)d_in[5];
  const float* GR   = (const float*)d_in[6];
  const float* GIm  = (const float*)d_in[7];
  const float* wm   = (const float*)d_in[8];
  const float* proj = (const float*)d_in[9];
  float* out = (float*)d_out;
  float* ws  = (float*)d_ws;

  n1_xm        <<<512, 256, 0, stream>>>(x, Wc, bc, ws + OFF_XR, ws + OFF_XI);
  n2_trans_beta<<<NT * 16 + 64, 256, 0, stream>>>(GR, GIm, ws + OFF_XR, ws + OFF_XI,
                                                  wm, ws + OFF_TR, ws + OFF_BE);
  k5_g         <<<dim3(16, 4, 6), 256, 0, stream>>>(spi, spj, invs, ws + OFF_TR,
                                                    ws + OFF_BE, ws + OFF_GI, ws + OFF_GJ);
  k6_out       <<<dim3(24, 48), 256, 0, stream>>>(proj, ws + OFF_GI, ws + OFF_GJ, out);
}